// Round 6
// baseline (426.372 us; speedup 1.0000x reference)
//
#include <hip/hip_runtime.h>

typedef __attribute__((ext_vector_type(8))) short short8;
typedef __attribute__((ext_vector_type(4))) float f32x4;

__device__ __forceinline__ float bf2f(unsigned short u){
  return __uint_as_float(((unsigned int)u) << 16);
}
__device__ __forceinline__ unsigned short f2bf(float f){
  unsigned int u = __float_as_uint(f);
  u += 0x7fffu + ((u >> 16) & 1u);   // RNE
  return (unsigned short)(u >> 16);
}
// dtype-dispatching scalar load: isF32 ? f32[i] : bf16[i]
__device__ __forceinline__ float ldf(const void* p, long i, int isF32){
  return isF32 ? ((const float*)p)[i] : bf2f(((const unsigned short*)p)[i]);
}

// ---- fp8 e4m3fn (OCP), branchless bit-trick codecs ----
// decode: place 7-bit exp+man at f32 exp/man, scale by 2^120.
// Exact for normals; fp8-denormals decode exactly too (or flush to 0
// if f32 DAZ, err <= 2^-9 -- negligible vs 0.25 tolerance).
__device__ __forceinline__ float fp8d(unsigned int u){
  unsigned int bits = ((u & 0x80u) << 24) | ((u & 0x7fu) << 20);
  return __uint_as_float(bits) * 0x1p120f;
}
// encode: scale into the window, RNE at bit 20, saturate to 448 (never NaN).
__device__ __forceinline__ unsigned int f2fp8(float f){
  float y = f * 0x1p-120f;
  unsigned int b = __float_as_uint(y);
  unsigned int s = (b >> 24) & 0x80u;
  b &= 0x7fffffffu;
  b += 0x7ffffu + ((b >> 20) & 1u);
  unsigned int m = b >> 20;
  if (m > 0x7eu) m = 0x7eu;
  return s | m;
}

// ---- prep: dtype detect (block 0) + row_ptr from sorted rows ----
__global__ void prep_k(const int* __restrict__ rows, int* __restrict__ rs,
                       int E, int N, const unsigned short* __restrict__ x,
                       int* __restrict__ flag){
  if (blockIdx.x == 0){
    __shared__ int s;
    if (threadIdx.x == 0) s = 0;
    __syncthreads();
    int bad = 0;
    for (int i = threadIdx.x; i < 2048; i += 256){
      unsigned int e = ((unsigned int)x[2 * i] >> 7) & 0xffu;
      if (e >= 0xF0u) bad = 1;
    }
    if (bad) atomicOr(&s, 1);
    __syncthreads();
    if (threadIdx.x == 0) *flag = s;
  }
  int e = blockIdx.x * 256 + threadIdx.x;
  if (e >= E) return;
  if (e == 0){
    for (int r = 0; r <= rows[0]; ++r) rs[r] = 0;
  } else {
    int a = rows[e - 1], b = rows[e];
    for (int r = a + 1; r <= b; ++r) rs[r] = e;
  }
  if (e == E - 1){
    for (int r = rows[E - 1] + 1; r <= N; ++r) rs[r] = E;
  }
}

// ---- fused transpose of all three W matrices -> canonical bf16 WT ----
__global__ void wtrans_all(const void* __restrict__ Wres,
                           const void* __restrict__ W1,
                           const void* __restrict__ W2,
                           unsigned short* __restrict__ WresT,
                           unsigned short* __restrict__ W1T,
                           unsigned short* __restrict__ W2T,
                           const int* __restrict__ flag){
  int isF32 = *flag;
  int b = blockIdx.x;
  const void* W; unsigned short* WT; int K; int idx;
  if (b < 128)      { W = Wres; WT = WresT; K = 256; idx = b * 256 + threadIdx.x; }
  else if (b < 256) { W = W1;   WT = W1T;   K = 256; idx = (b - 128) * 256 + threadIdx.x; }
  else              { W = W2;   WT = W2T;   K = 128; idx = (b - 256) * 256 + threadIdx.x; }
  if (idx >= K * 128) return;
  int n = idx / K, k = idx - n * K;
  WT[idx] = f2bf(ldf(W, (long)k * 128 + n, isF32));
}

// ============================================================
// Fused dual GEMM (R2-measured 117us structure): z = x@Wres+bres
// (bf16), y1 = x@W1 (fp8 e4m3), one A-read.  2 waves/SIMD.
// ============================================================
__global__ __launch_bounds__(256, 2) void gemm_zy1(
    const void* __restrict__ A,
    const unsigned short* __restrict__ WT0,  // WresT [128][256]
    const unsigned short* __restrict__ WT1,  // W1T   [128][256]
    const void* __restrict__ bias0,
    unsigned short* __restrict__ out0,       // z  [M][128] bf16
    unsigned char*  __restrict__ out1,       // y1 [M][128] fp8
    int M, const int* __restrict__ flagp)
{
  constexpr int K = 256, KB = 128;
  __shared__ __align__(16) unsigned short lW[2 * 128 * 128];  // 64 KB

  const int fl   = *flagp;
  const int tid  = threadIdx.x;
  const int lane = tid & 63;
  const int wav  = tid >> 6;
  const int l16  = lane & 15;
  const int quad = lane >> 4;
  const int rowBase = blockIdx.x * 128 + wav * 32;

  f32x4 acc[2][2][8];   // [plane][s][nt]
#pragma unroll
  for (int w = 0; w < 2; ++w)
#pragma unroll
    for (int s = 0; s < 2; ++s)
#pragma unroll
      for (int nt = 0; nt < 8; ++nt) acc[w][s][nt] = (f32x4){0.f, 0.f, 0.f, 0.f};

  for (int kb = 0; kb < K; kb += KB){
    __syncthreads();
#pragma unroll
    for (int i = tid; i < 2 * 128 * 16; i += 256){
      int t = i >> 11;
      int j = i & 2047;
      int n = j >> 4;
      int c = j & 15;
      const unsigned short* WT = t ? WT1 : WT0;
      *(short8*)&lW[(t * 128 + n) * 128 + ((c * 8) ^ ((n & 7) * 8))] =
          *(const short8*)&WT[n * K + kb + c * 8];
    }
    short8 af[2][4];
    if (fl){
#pragma unroll
      for (int s = 0; s < 2; ++s){
        int r = rowBase + s * 16 + l16;
        const float* Af = (const float*)A + (long)r * K + kb + quad * 8;
        f32x4 t0[4], t1[4];
#pragma unroll
        for (int q = 0; q < 4; ++q){
          if (r < M){
            t0[q] = *(const f32x4*)(Af + q * 32);
            t1[q] = *(const f32x4*)(Af + q * 32 + 4);
          } else {
            t0[q] = (f32x4){0.f, 0.f, 0.f, 0.f};
            t1[q] = (f32x4){0.f, 0.f, 0.f, 0.f};
          }
        }
#pragma unroll
        for (int q = 0; q < 4; ++q){
          short8 v;
          v[0] = (short)f2bf(t0[q][0]); v[1] = (short)f2bf(t0[q][1]);
          v[2] = (short)f2bf(t0[q][2]); v[3] = (short)f2bf(t0[q][3]);
          v[4] = (short)f2bf(t1[q][0]); v[5] = (short)f2bf(t1[q][1]);
          v[6] = (short)f2bf(t1[q][2]); v[7] = (short)f2bf(t1[q][3]);
          af[s][q] = v;
        }
      }
    } else {
#pragma unroll
      for (int s = 0; s < 2; ++s){
        int r = rowBase + s * 16 + l16;
        const unsigned short* Ab = (const unsigned short*)A + (long)r * K + kb + quad * 8;
#pragma unroll
        for (int q = 0; q < 4; ++q){
          short8 v = {};
          if (r < M) v = *(const short8*)(Ab + q * 32);
          af[s][q] = v;
        }
      }
    }
    __syncthreads();
#pragma unroll
    for (int q = 0; q < 4; ++q){
#pragma unroll
      for (int nt = 0; nt < 8; ++nt){
        int row = nt * 16 + l16;
        int bo  = row * 128 + ((q * 32 + quad * 8) ^ ((row & 7) * 8));
        short8 b0 = *(const short8*)&lW[bo];
        short8 b1 = *(const short8*)&lW[128 * 128 + bo];
        acc[0][0][nt] = __builtin_amdgcn_mfma_f32_16x16x32_bf16(af[0][q], b0, acc[0][0][nt], 0, 0, 0);
        acc[0][1][nt] = __builtin_amdgcn_mfma_f32_16x16x32_bf16(af[1][q], b0, acc[0][1][nt], 0, 0, 0);
        acc[1][0][nt] = __builtin_amdgcn_mfma_f32_16x16x32_bf16(af[0][q], b1, acc[1][0][nt], 0, 0, 0);
        acc[1][1][nt] = __builtin_amdgcn_mfma_f32_16x16x32_bf16(af[1][q], b1, acc[1][1][nt], 0, 0, 0);
      }
    }
  }

#pragma unroll
  for (int s = 0; s < 2; ++s){
    int r0 = rowBase + s * 16 + quad * 4;
#pragma unroll
    for (int nt = 0; nt < 8; ++nt){
      int col = nt * 16 + l16;
      float bv = ldf(bias0, col, fl);
#pragma unroll
      for (int rg = 0; rg < 4; ++rg){
        int r = r0 + rg;
        if (r < M){
          out0[(long)r * 128 + col] = f2bf(acc[0][s][nt][rg] + bv);      // z bf16
          out1[(long)r * 128 + col] = (unsigned char)f2fp8(acc[1][s][nt][rg]); // y1 fp8
        }
      }
    }
  }
}

// ============================================================
// y2 GEMM (R2 structure): y2 = x1(bf16)@W2 -> fp8 out.
// ============================================================
__global__ __launch_bounds__(256, 3) void gemm_y2(
    const unsigned short* __restrict__ A,    // x1 bf16 [M][128]
    const unsigned short* __restrict__ WT,   // W2T [128][128]
    unsigned char* __restrict__ out,         // y2 fp8 [M][128]
    int M)
{
  constexpr int K = 128;
  __shared__ __align__(16) unsigned short lW[128 * 128];   // 32 KB

  const int tid  = threadIdx.x;
  const int lane = tid & 63;
  const int wav  = tid >> 6;
  const int l16  = lane & 15;
  const int quad = lane >> 4;
  const int rowBase = blockIdx.x * 128 + wav * 32;

#pragma unroll
  for (int i = tid; i < 128 * 16; i += 256){
    int n = i >> 4;
    int c = i & 15;
    *(short8*)&lW[n * 128 + ((c * 8) ^ ((n & 7) * 8))] = *(const short8*)&WT[n * K + c * 8];
  }
  short8 af[2][4];
#pragma unroll
  for (int s = 0; s < 2; ++s){
    int r = rowBase + s * 16 + l16;
    const unsigned short* Ab = A + (long)r * K + quad * 8;
#pragma unroll
    for (int q = 0; q < 4; ++q){
      short8 v = {};
      if (r < M) v = *(const short8*)(Ab + q * 32);
      af[s][q] = v;
    }
  }
  f32x4 acc[2][8];
#pragma unroll
  for (int s = 0; s < 2; ++s)
#pragma unroll
    for (int nt = 0; nt < 8; ++nt) acc[s][nt] = (f32x4){0.f, 0.f, 0.f, 0.f};
  __syncthreads();
#pragma unroll
  for (int q = 0; q < 4; ++q){
#pragma unroll
    for (int nt = 0; nt < 8; ++nt){
      int row = nt * 16 + l16;
      short8 b = *(const short8*)&lW[row * 128 + ((q * 32 + quad * 8) ^ ((row & 7) * 8))];
      acc[0][nt] = __builtin_amdgcn_mfma_f32_16x16x32_bf16(af[0][q], b, acc[0][nt], 0, 0, 0);
      acc[1][nt] = __builtin_amdgcn_mfma_f32_16x16x32_bf16(af[1][q], b, acc[1][nt], 0, 0, 0);
    }
  }
#pragma unroll
  for (int s = 0; s < 2; ++s){
    int r0 = rowBase + s * 16 + quad * 4;
#pragma unroll
    for (int nt = 0; nt < 8; ++nt){
      int col = nt * 16 + l16;
#pragma unroll
      for (int rg = 0; rg < 4; ++rg){
        int r = r0 + rg;
        if (r < M) out[(long)r * 128 + col] = (unsigned char)f2fp8(acc[s][nt][rg]);
      }
    }
  }
}

// ---- R0-measured gather, fp8 Y: 1 line/edge, 2 feats/lane (ushort) ----
__device__ __forceinline__ void row_gather_f8(
    int e0, int e1, const int* __restrict__ cols, const void* __restrict__ vals,
    const unsigned char* __restrict__ Y, int lane, int fl,
    float& outx, float& outy)
{
  float ax0 = 0.f, ay0 = 0.f, ax1 = 0.f, ay1 = 0.f;
  int e = e0;
  for (; e + 4 <= e1; e += 4){
    int c0 = cols[e], c1 = cols[e + 1], c2 = cols[e + 2], c3 = cols[e + 3];
    float v0 = ldf(vals, e, fl),     v1 = ldf(vals, e + 1, fl);
    float v2 = ldf(vals, e + 2, fl), v3 = ldf(vals, e + 3, fl);
    unsigned int q0 = *(const unsigned short*)&Y[(long)c0 * 128 + 2 * lane];
    unsigned int q1 = *(const unsigned short*)&Y[(long)c1 * 128 + 2 * lane];
    unsigned int q2 = *(const unsigned short*)&Y[(long)c2 * 128 + 2 * lane];
    unsigned int q3 = *(const unsigned short*)&Y[(long)c3 * 128 + 2 * lane];
    ax0 = fmaf(v0, fp8d(q0 & 0xffu), ax0);
    ay0 = fmaf(v0, fp8d(q0 >> 8),    ay0);
    ax1 = fmaf(v1, fp8d(q1 & 0xffu), ax1);
    ay1 = fmaf(v1, fp8d(q1 >> 8),    ay1);
    ax0 = fmaf(v2, fp8d(q2 & 0xffu), ax0);
    ay0 = fmaf(v2, fp8d(q2 >> 8),    ay0);
    ax1 = fmaf(v3, fp8d(q3 & 0xffu), ax1);
    ay1 = fmaf(v3, fp8d(q3 >> 8),    ay1);
  }
  for (; e < e1; ++e){
    int c = cols[e];
    float v = ldf(vals, e, fl);
    unsigned int q = *(const unsigned short*)&Y[(long)c * 128 + 2 * lane];
    ax0 = fmaf(v, fp8d(q & 0xffu), ax0);
    ay0 = fmaf(v, fp8d(q >> 8),    ay0);
  }
  outx = ax0 + ax1;
  outy = ay0 + ay1;
}

// ---- spmm1 fused: x1[r] = relu(spmm(y1)[r] + b1) + z[r], bf16 out ----
__global__ __launch_bounds__(256) void spmm1_f(
    const int* __restrict__ rs, const int* __restrict__ cols,
    const void* __restrict__ vals, const unsigned char* __restrict__ Y,
    const unsigned short* __restrict__ z, const void* __restrict__ b1,
    unsigned short* __restrict__ x1, int N, const int* __restrict__ flagp)
{
  const int fl   = *flagp;
  const int lane = threadIdx.x & 63;
  const int wav  = threadIdx.x >> 6;
  int r = blockIdx.x * 4 + wav;
  if (r >= N) return;
  int e0 = __builtin_amdgcn_readfirstlane(rs[r]);
  int e1 = __builtin_amdgcn_readfirstlane(rs[r + 1]);
  float ax, ay;
  row_gather_f8(e0, e1, cols, vals, Y, lane, fl, ax, ay);
  long o = (long)r * 128 + 2 * lane;
  float b0 = ldf(b1, 2 * lane, fl), b1v = ldf(b1, 2 * lane + 1, fl);
  unsigned int zz = *(const unsigned int*)&z[o];
  float r0 = fmaxf(ax + b0,  0.f) + bf2f((unsigned short)(zz & 0xffffu));
  float r1 = fmaxf(ay + b1v, 0.f) + bf2f((unsigned short)(zz >> 16));
  *(unsigned int*)&x1[o] = (unsigned int)f2bf(r0) | ((unsigned int)f2bf(r1) << 16);
}

// ---- spmm2 fused: out[r] = log_softmax(spmm(y2)[r] + b2), dtype per flag ----
__global__ __launch_bounds__(256) void spmm2_f(
    const int* __restrict__ rs, const int* __restrict__ cols,
    const void* __restrict__ vals, const unsigned char* __restrict__ Y,
    const void* __restrict__ b2, void* __restrict__ out, int N,
    const int* __restrict__ flagp)
{
  const int fl   = *flagp;
  const int lane = threadIdx.x & 63;
  const int wav  = threadIdx.x >> 6;
  int r = blockIdx.x * 4 + wav;
  if (r >= N) return;
  int e0 = __builtin_amdgcn_readfirstlane(rs[r]);
  int e1 = __builtin_amdgcn_readfirstlane(rs[r + 1]);
  float ax, ay;
  row_gather_f8(e0, e1, cols, vals, Y, lane, fl, ax, ay);
  float v0 = ax + ldf(b2, 2 * lane, fl);
  float v1 = ay + ldf(b2, 2 * lane + 1, fl);
  float m = fmaxf(v0, v1);
#pragma unroll
  for (int off = 32; off; off >>= 1) m = fmaxf(m, __shfl_xor(m, off));
  float s = expf(v0 - m) + expf(v1 - m);
#pragma unroll
  for (int off = 32; off; off >>= 1) s += __shfl_xor(s, off);
  float lse = m + logf(s);
  long o = (long)r * 128 + 2 * lane;
  if (fl){
    float2 w; w.x = v0 - lse; w.y = v1 - lse;
    *(float2*)&((float*)out)[o] = w;
  } else {
    *(unsigned int*)&((unsigned short*)out)[o] =
        (unsigned int)f2bf(v0 - lse) | ((unsigned int)f2bf(v1 - lse) << 16);
  }
}

extern "C" void kernel_launch(void* const* d_in, const int* in_sizes, int n_in,
                              void* d_out, int out_size, void* d_ws, size_t ws_size,
                              hipStream_t stream)
{
  const void* x    = d_in[0];
  const int*  erow = (const int*)d_in[1];
  const int*  ecol = (const int*)d_in[2];
  const void* eval = d_in[3];
  const void* Wres = d_in[4];
  const void* bres = d_in[5];
  const void* W1   = d_in[6];
  const void* b1   = d_in[7];
  const void* W2   = d_in[8];
  const void* b2   = d_in[9];
  const int N = in_sizes[0] / 256;   // 100000
  const int E = in_sizes[1];         // 1600000

  char* ws = (char*)d_ws;
  size_t szB = (size_t)N * 128 * 2;  // one bf16 [N,128] plane (25.6 MB)
  unsigned char*  yf8   = (unsigned char*)ws;             // y1 fp8, then y2 fp8
  unsigned short* bufC  = (unsigned short*)(ws + szB);    // x1 bf16
  unsigned short* WresT = (unsigned short*)(ws + 2 * szB);
  unsigned short* W1T   = WresT + 256 * 128;
  unsigned short* W2T   = W1T   + 256 * 128;
  int*            flag  = (int*)(W2T + 256 * 128);
  int*            rs    = flag + 4;                        // [N+1] row_ptr
  unsigned short* zbuf  = (unsigned short*)d_out;          // z (bf16) in d_out

  prep_k<<<(E + 255) / 256, 256, 0, stream>>>(erow, rs, E, N,
                                              (const unsigned short*)x, flag);
  wtrans_all<<<320, 256, 0, stream>>>(Wres, W1, W2, WresT, W1T, W2T, flag);

  const int gBlocks = (N + 127) / 128;
  const int rBlocks = (N + 3) / 4;

  gemm_zy1<<<gBlocks, 256, 0, stream>>>(x, WresT, W1T, bres, zbuf, yf8, N, flag); // z + y1(fp8)

  spmm1_f<<<rBlocks, 256, 0, stream>>>(rs, ecol, eval, yf8, zbuf, b1, bufC, N, flag); // x1

  gemm_y2<<<gBlocks, 256, 0, stream>>>(bufC, W2T, yf8, N);                            // y2(fp8)

  spmm2_f<<<rBlocks, 256, 0, stream>>>(rs, ecol, eval, yf8, b2, d_out, N, flag);      // out
}